// Round 11
// baseline (768.274 us; speedup 1.0000x reference)
//
#include <hip/hip_runtime.h>
#include <math.h>

// KSIZE=3, STRIDE=1, RATE=2, FUSE_K=3, SCALE=10
#define CDIM 128
#define HF   128
#define WF   128
#define NP   4096   // 64*64 downsampled positions
#define NCHUNK 64   // softmax u-chunks (64 rows each)

typedef __attribute__((ext_vector_type(8))) short short8;
typedef float __attribute__((ext_vector_type(4), aligned(16))) f4a16;
typedef float __attribute__((ext_vector_type(4), aligned(4)))  f4u;

__device__ inline ushort f2bf(float x) {
  union { float f; unsigned u; } v; v.f = x;
  unsigned r = v.u + 0x7fff + ((v.u >> 16) & 1);
  return (ushort)(r >> 16);
}
__device__ inline float bf2f(ushort h) {
  union { unsigned u; float f; } v; v.u = ((unsigned)h) << 16; return v.f;
}

__device__ inline void gl2lds16(const ushort* g, ushort* l) {
  __builtin_amdgcn_global_load_lds((const __attribute__((address_space(1))) void*)g,
                                   (__attribute__((address_space(3))) void*)l, 16, 0, 0);
}

// ---------------------------------------------------------------------------
// prep: downsample + split fp32 -> (hi,lo) bf16 K-major cat operands, AND
// s2[p] = sum_c b_ds[c,p]^2
__global__ __launch_bounds__(256) void k_prep(const float* __restrict__ f,
                                              const float* __restrict__ b,
                                              ushort* __restrict__ fcat,
                                              ushort* __restrict__ bcat,
                                              float* __restrict__ s2) {
  int idx = blockIdx.x * 256 + threadIdx.x;   // 524288
  int c = idx & 127, pos = idx >> 7;
  int x = pos & 63, y = pos >> 6;
  int src = c * 16384 + y * 256 + x * 2;
  float fv = f[src], bv = b[src];
  ushort fh = f2bf(fv); ushort fl = f2bf(fv - bf2f(fh));
  ushort bh = f2bf(bv); ushort bl = f2bf(bv - bf2f(bh));
  size_t base = (size_t)pos * 384;
  fcat[base + c] = fh; fcat[base + 128 + c] = fl; fcat[base + 256 + c] = fh;
  bcat[base + c] = bh; bcat[base + 128 + c] = bh; bcat[base + 256 + c] = bl;
  float sq = bv * bv;
#pragma unroll
  for (int off = 32; off; off >>= 1) sq += __shfl_down(sq, off);
  __shared__ float wsum[4];
  if ((threadIdx.x & 63) == 0) wsum[threadIdx.x >> 6] = sq;
  __syncthreads();
  if (threadIdx.x == 0) s2[blockIdx.x * 2]     = wsum[0] + wsum[1];
  if (threadIdx.x == 1) s2[blockIdx.x * 2 + 1] = wsum[2] + wsum[3];
}

// merged: blocks 0..15 -> mmp[a] (mask gate at p=pi(a)); 16..31 -> rnrm[p]
__global__ __launch_bounds__(256) void k_mmpnorm(const float* __restrict__ mask,
                                                 const float* __restrict__ s2,
                                                 float* __restrict__ mmp,
                                                 float* __restrict__ rnrm) {
  int bx = blockIdx.x, t = threadIdx.x;
  if (bx < 16) {
    int a = bx * 256 + t;
    int yb = a & 63, xb = a >> 6;               // p = pi(a)
    float s = 0.f;
    for (int dy = -1; dy <= 1; ++dy)
      for (int dx = -1; dx <= 1; ++dx) {
        int y = yb + dy, x = xb + dx;
        if ((unsigned)y < 64u && (unsigned)x < 64u)
          s += mask[y * 256 + x * 2];
      }
    mmp[a] = (s == 0.0f) ? 1.0f : 0.0f;
  } else {
    int p = (bx - 16) * 256 + t;
    int xb = p & 63, yb = p >> 6;
    float s = 0.f;
    for (int dy = -1; dy <= 1; ++dy)
      for (int dx = -1; dx <= 1; ++dx) {
        int y = yb + dy, x = xb + dx;
        if ((unsigned)y < 64u && (unsigned)x < 64u) s += s2[y * 64 + x];
      }
    rnrm[p] = rsqrtf(s + 1152.0f * 1.0e-4f);
  }
}

// ---------------------------------------------------------------------------
// MFMA bf16 GEMM (score): Out[m,n] = sum_k A[m*lda+k]*B[n*ldb+k]
// 128x128 tile, 4 waves, BK=64, global_load_lds + global-address XOR swizzle.
__global__ __launch_bounds__(256) void k_mfma_gemm(const ushort* __restrict__ A,
                                                   const ushort* __restrict__ B,
                                                   float* __restrict__ Out,
                                                   int Kdim, int lda, int ldb, int ldo) {
  __shared__ ushort As[128 * 64];
  __shared__ ushort Bs[128 * 64];
  int tid = threadIdx.x;
  int wave = tid >> 6, lane = tid & 63;
  int quad = lane >> 4, l16 = lane & 15;
  int m0 = blockIdx.y * 128, n0 = blockIdx.x * 128;
  int wm = (wave >> 1) * 64, wn = (wave & 1) * 64;
  int srow = lane >> 3;
  int g = lane & 7;
  int gperm = (g ^ srow) * 8;

  f4a16 acc[4][4];
#pragma unroll
  for (int i = 0; i < 4; ++i)
#pragma unroll
    for (int j = 0; j < 4; ++j) acc[i][j] = (f4a16){0.f, 0.f, 0.f, 0.f};

  for (int k0 = 0; k0 < Kdim; k0 += 64) {
#pragma unroll
    for (int i = 0; i < 4; ++i) {
      int rbase = wave * 32 + i * 8;
      gl2lds16(A + (size_t)(m0 + rbase + srow) * lda + k0 + gperm, &As[rbase * 64]);
      gl2lds16(B + (size_t)(n0 + rbase + srow) * ldb + k0 + gperm, &Bs[rbase * 64]);
    }
    __syncthreads();
#pragma unroll
    for (int s = 0; s < 2; ++s) {
      short8 afrag[4], bfrag[4];
#pragma unroll
      for (int t = 0; t < 4; ++t) {
        int am = wm + t * 16 + l16;
        int ga = ((s * 4 + quad) ^ (am & 7)) * 8;
        afrag[t] = *reinterpret_cast<const short8*>(&As[am * 64 + ga]);
        int bn = wn + t * 16 + l16;
        int gb = ((s * 4 + quad) ^ (bn & 7)) * 8;
        bfrag[t] = *reinterpret_cast<const short8*>(&Bs[bn * 64 + gb]);
      }
#pragma unroll
      for (int i = 0; i < 4; ++i)
#pragma unroll
        for (int j = 0; j < 4; ++j)
          acc[i][j] = __builtin_amdgcn_mfma_f32_16x16x32_bf16(afrag[i], bfrag[j], acc[i][j], 0, 0, 0);
    }
    __syncthreads();
  }
#pragma unroll
  for (int i = 0; i < 4; ++i)
#pragma unroll
    for (int j = 0; j < 4; ++j)
#pragma unroll
      for (int r = 0; r < 4; ++r)
        Out[(size_t)(m0 + wm + i * 16 + quad * 4 + r) * ldo + (n0 + wn + j * 16 + l16)] = acc[i][j][r];
}

// Value GEMM with FUSED transposed-conv scatter epilogue:
// M[k2,q] = sum_a VtT[k2,a]*AT[q,a]; each (k2=(c,dy,dx), q=(qy,qx)) maps to the
// single output pixel (c, 2qy+dy-1, 2qx+dx-1) -> atomicAdd(0.25*acc) into
// pre-zeroed out. Deletes the M buffer + scatter pass entirely.
__global__ __launch_bounds__(256) void k_mfma_gemm_vout(const ushort* __restrict__ A,
                                                        const ushort* __restrict__ B,
                                                        float* __restrict__ out) {
  __shared__ ushort As[128 * 64];
  __shared__ ushort Bs[128 * 64];
  int tid = threadIdx.x;
  int wave = tid >> 6, lane = tid & 63;
  int quad = lane >> 4, l16 = lane & 15;
  int m0 = blockIdx.y * 128, n0 = blockIdx.x * 128;
  int wm = (wave >> 1) * 64, wn = (wave & 1) * 64;
  int srow = lane >> 3;
  int g = lane & 7;
  int gperm = (g ^ srow) * 8;

  f4a16 acc[4][4];
#pragma unroll
  for (int i = 0; i < 4; ++i)
#pragma unroll
    for (int j = 0; j < 4; ++j) acc[i][j] = (f4a16){0.f, 0.f, 0.f, 0.f};

  for (int k0 = 0; k0 < NP; k0 += 64) {
#pragma unroll
    for (int i = 0; i < 4; ++i) {
      int rbase = wave * 32 + i * 8;
      gl2lds16(A + (size_t)(m0 + rbase + srow) * NP + k0 + gperm, &As[rbase * 64]);
      gl2lds16(B + (size_t)(n0 + rbase + srow) * NP + k0 + gperm, &Bs[rbase * 64]);
    }
    __syncthreads();
#pragma unroll
    for (int s = 0; s < 2; ++s) {
      short8 afrag[4], bfrag[4];
#pragma unroll
      for (int t = 0; t < 4; ++t) {
        int am = wm + t * 16 + l16;
        int ga = ((s * 4 + quad) ^ (am & 7)) * 8;
        afrag[t] = *reinterpret_cast<const short8*>(&As[am * 64 + ga]);
        int bn = wn + t * 16 + l16;
        int gb = ((s * 4 + quad) ^ (bn & 7)) * 8;
        bfrag[t] = *reinterpret_cast<const short8*>(&Bs[bn * 64 + gb]);
      }
#pragma unroll
      for (int i = 0; i < 4; ++i)
#pragma unroll
        for (int j = 0; j < 4; ++j)
          acc[i][j] = __builtin_amdgcn_mfma_f32_16x16x32_bf16(afrag[i], bfrag[j], acc[i][j], 0, 0, 0);
    }
    __syncthreads();
  }
  // scatter epilogue
#pragma unroll
  for (int i = 0; i < 4; ++i)
#pragma unroll
    for (int r = 0; r < 4; ++r) {
      int k2 = m0 + wm + i * 16 + quad * 4 + r;
      int c = k2 >> 4, dy = (k2 >> 2) & 3, dxv = k2 & 3;
#pragma unroll
      for (int j = 0; j < 4; ++j) {
        int q = n0 + wn + j * 16 + l16;
        int oy = 2 * (q >> 6) + dy - 1;
        int ox = 2 * (q & 63) + dxv - 1;
        if ((unsigned)oy < 128u && (unsigned)ox < 128u)
          atomicAdd(&out[c * 16384 + oy * 128 + ox], 0.25f * acc[i][j][r]);
      }
    }
}

// ---------------------------------------------------------------------------
// S0[p,q] = (sum of 9 diag-shifted D taps) * rnrm[p]
__global__ __launch_bounds__(256) void k_s0(const float* __restrict__ D,
                                            const float* __restrict__ rnrm,
                                            float* __restrict__ S0) {
  int p = blockIdx.x;
  int yb = p >> 6, xb = p & 63;
  float rp = rnrm[p];
  int t = threadIdx.x;
#pragma unroll
  for (int it = 0; it < 4; ++it) {
    int q = (it * 256 + t) << 2;
    int qy = q >> 6, qx = q & 63;
    f4a16 acc = (f4a16){0.f, 0.f, 0.f, 0.f};
#pragma unroll
    for (int dy = -1; dy <= 1; ++dy) {
      if ((unsigned)(yb + dy) >= 64u) continue;
      if ((unsigned)(qy + dy) >= 64u) continue;
#pragma unroll
      for (int dx = -1; dx <= 1; ++dx) {
        if ((unsigned)(xb + dx) >= 64u) continue;
        int delta = dy * 64 + dx;
        const float* base = D + (size_t)(p + delta) * 4096;
        f4u v;
        if (dx == -1 && qx == 0) {
          f4u r = *(const f4u*)(base + q + delta + 1);  // avoid negative addr
          v = (f4u){0.f, r.x, r.y, r.z};
        } else {
          v = *(const f4u*)(base + q + delta);
          if (dx == 1 && qx == 60) v.w = 0.f;
        }
        acc += v;
      }
    }
    acc *= rp;
    *(f4a16*)(S0 + ((size_t)p << 12) + q) = acc;
  }
}

// fuse1: F1[i,j] = sum_d S0[i+d, j+d], written permuted: Yp[pi(i)][b]=F1[i][pi(b)]
__global__ __launch_bounds__(256) void k_fuse1(const float* __restrict__ S0,
                                               float* __restrict__ Yp) {
  __shared__ float row[4160];
  int i = blockIdx.x;
  int t = threadIdx.x;
  const float* r0 = S0 + (size_t)(i - 1) * 4096;
  const float* r1 = S0 + (size_t)i * 4096;
  const float* r2 = S0 + (size_t)(i + 1) * 4096;
  bool up = (i > 0), dn = (i < 4095);
#pragma unroll
  for (int jj = 0; jj < 4; ++jj) {
    int j = (jj * 256 + t) << 2;
    f4u s = *(const f4u*)(r1 + j);
    if (up) {
      f4u a;
      if (j == 0) { f4u r = *(const f4u*)r0; a = (f4u){0.f, r.x, r.y, r.z}; }
      else a = *(const f4u*)(r0 + j - 1);
      s += a;
    }
    if (dn) {
      f4u d = *(const f4u*)(r2 + j + 1);
      if (j == 4092) d.w = 0.f;
      s += d;
    }
    int base = j + (j >> 6);
    row[base + 0] = s.x; row[base + 1] = s.y; row[base + 2] = s.z; row[base + 3] = s.w;
  }
  __syncthreads();
  int a = ((i & 63) << 6) | (i >> 6);
  float* orow = Yp + ((size_t)a << 12);
#pragma unroll
  for (int bb = 0; bb < 4; ++bb) {
    int b4 = (bb * 256 + t) << 2;
    f4a16 o;
#pragma unroll
    for (int k = 0; k < 4; ++k) {
      int jT = (((b4 + k) & 63) << 6) | ((b4 + k) >> 6);
      o[k] = row[jT + (jT >> 6)];
    }
    *(f4a16*)(orow + b4) = o;
  }
}

// softmax partials over u of logits x = 10 * mmp[u] * diag3(Yp)[u,v]
__global__ __launch_bounds__(256) void k_smax_part(const float* __restrict__ Yp,
                                                   const float* __restrict__ mmp,
                                                   float* __restrict__ pm,
                                                   float* __restrict__ ps) {
  int v = (blockIdx.x * 256 + threadIdx.x) << 2;
  int chunk = blockIdx.y;
  f4a16 m = (f4a16){-1e30f, -1e30f, -1e30f, -1e30f};
  f4a16 s = (f4a16){0.f, 0.f, 0.f, 0.f};
  int u0 = chunk * (4096 / NCHUNK);
  for (int u = u0; u < u0 + (4096 / NCHUNK); ++u) {
    const float* row = Yp + ((size_t)u << 12);
    f4u tv = *(const f4u*)(row + v);
    if (u > 0) {
      f4u a;
      if (v == 0) { f4u r = *(const f4u*)(row - 4096); a = (f4u){0.f, r.x, r.y, r.z}; }
      else a = *(const f4u*)(row - 4096 + v - 1);
      tv += a;
    }
    if (u < 4095) {
      f4u d = *(const f4u*)(row + 4096 + v + 1);
      if (v == 4092) d.w = 0.f;
      tv += d;
    }
    float g = 10.0f * mmp[u];
    f4u x = tv * g;
#pragma unroll
    for (int l = 0; l < 4; ++l) {
      float xl = x[l];
      if (xl > m[l]) { s[l] = s[l] * __expf(m[l] - xl) + 1.0f; m[l] = xl; }
      else           { s[l] += __expf(xl - m[l]); }
    }
  }
  *(f4a16*)(pm + chunk * NP + v) = m;
  *(f4a16*)(ps + chunk * NP + v) = s;
}

// ---------------------------------------------------------------------------
// epilogue (flattened 6144-block grid): attnT tiles w/ local softmax reduction,
// and VtT transpose blocks.
__global__ __launch_bounds__(256) void k_epilogue(const float* __restrict__ Yp,
                                                  const float* __restrict__ pm,
                                                  const float* __restrict__ ps,
                                                  const float* __restrict__ mmp,
                                                  ushort* __restrict__ AT,
                                                  const float* __restrict__ bimg,
                                                  ushort* __restrict__ VtT) {
  __shared__ float T[64][65];
  __shared__ float pmS[4][64];
  __shared__ float psS[4][64];
  __shared__ float mS[64];
  __shared__ float rsS[64];
  int gx = blockIdx.x;
  int t = threadIdx.x;
  if (gx < 4096) {
    int a0 = (gx & 63) * 64, b0 = (gx >> 6) * 64;
    int j = t & 63, grp = t >> 6;
    float m = -1e30f, s = 0.f;
    for (int ch = grp * 16; ch < grp * 16 + 16; ++ch) {
      float m2 = pm[ch * NP + b0 + j], s2 = ps[ch * NP + b0 + j];
      if (m2 > m) { s = s * __expf(m - m2) + s2; m = m2; }
      else        { s += s2 * __expf(m2 - m); }
    }
    pmS[grp][j] = m; psS[grp][j] = s;
    __syncthreads();
    if (grp == 0) {
      for (int g2 = 1; g2 < 4; ++g2) {
        float m2 = pmS[g2][j], s2 = psS[g2][j];
        if (m2 > m) { s = s * __expf(m - m2) + s2; m = m2; }
        else        { s += s2 * __expf(m2 - m); }
      }
      mS[j] = m; rsS[j] = 1.0f / s;
    }
    __syncthreads();
    int i = t >> 4, j4 = (t & 15) << 2;
    f4a16 mc = *(const f4a16*)&mS[j4];
    f4a16 rs = *(const f4a16*)&rsS[j4];
#pragma unroll
    for (int r = 0; r < 4; ++r) {
      int al = r * 16 + i;
      int a = a0 + al;
      const float* row = Yp + ((size_t)a << 12);
      int b = b0 + j4;
      f4u y = *(const f4u*)(row + b);
      if (a > 0) {
        f4u u_;
        if (b == 0) { f4u rr = *(const f4u*)(row - 4096); u_ = (f4u){0.f, rr.x, rr.y, rr.z}; }
        else u_ = *(const f4u*)(row - 4096 + b - 1);
        y += u_;
      }
      if (a < 4095) {
        f4u d = *(const f4u*)(row + 4096 + b + 1);
        if (b == 4092) d.w = 0.f;
        y += d;
      }
      float g = mmp[a];
      f4u x = y * (10.0f * g);
#pragma unroll
      for (int l = 0; l < 4; ++l)
        T[al][j4 + l] = g * __expf(x[l] - mc[l]) * rs[l];
    }
    __syncthreads();
    int by0 = b0 >> 6;
    int cgrp = (t & 7) * 8;
#pragma unroll
    for (int pass = 0; pass < 2; ++pass) {
      int bl = pass * 32 + (t >> 3);
      int q = bl * 64 + by0;                   // pi(b0 + bl)
      uint4 w;
      w.x = (unsigned)f2bf(T[cgrp + 0][bl]) | ((unsigned)f2bf(T[cgrp + 1][bl]) << 16);
      w.y = (unsigned)f2bf(T[cgrp + 2][bl]) | ((unsigned)f2bf(T[cgrp + 3][bl]) << 16);
      w.z = (unsigned)f2bf(T[cgrp + 4][bl]) | ((unsigned)f2bf(T[cgrp + 5][bl]) << 16);
      w.w = (unsigned)f2bf(T[cgrp + 6][bl]) | ((unsigned)f2bf(T[cgrp + 7][bl]) << 16);
      *(uint4*)(AT + ((size_t)q << 12) + a0 + cgrp) = w;
    }
  } else {
    int k2 = gx - 4096;
    int c = k2 >> 4, dy = (k2 >> 2) & 3, dx = k2 & 3;
    int px = t & 63;
#pragma unroll
    for (int r = 0; r < 16; ++r) {
      int py = r * 4 + (t >> 6);
      int sy = 2 * py + dy - 1, sx = 2 * px + dx - 1;
      float v = 0.f;
      if ((unsigned)sy < (unsigned)HF && (unsigned)sx < (unsigned)WF)
        v = bimg[c * 16384 + sy * 128 + sx];
      T[py][px] = v;
    }
    __syncthreads();
    ushort* orow = VtT + (size_t)k2 * 4096;
#pragma unroll
    for (int r = 0; r < 16; ++r) {
      int a = r * 256 + t;
      orow[a] = f2bf(T[a & 63][a >> 6]);
    }
  }
}

// ---------------------------------------------------------------------------
extern "C" void kernel_launch(void* const* d_in, const int* in_sizes, int n_in,
                              void* d_out, int out_size, void* d_ws, size_t ws_size,
                              hipStream_t stream) {
  const float* f_all = (const float*)d_in[0];
  const float* b_all = (const float*)d_in[1];
  const float* m_all = (const float*)d_in[2];
  float* out = (float*)d_out;

  float* ws = (float*)d_ws;
  float* bufD = ws;                          // 64MB: D -> Yp
  float* bufS = ws + 16777216;               // 64MB: {fcat,bcat} -> S0 -> {AT, VtT}
  ushort* fcat = (ushort*)bufS;
  ushort* bcat = (ushort*)(bufS + 786432);
  float* S0  = bufS;
  float* Yp  = bufD;
  ushort* AT  = (ushort*)bufS;               // 32MB
  ushort* VtT = (ushort*)(bufS + 8388608);   // 16MB
  float* smalls = ws + 2 * 16777216;
  float* s2    = smalls;
  float* rnrm  = s2 + 4096;
  float* mmp   = rnrm + 4096;
  float* pm    = mmp + 4096;
  float* ps    = pm + NCHUNK * NP;

  const size_t zsF = (size_t)CDIM * HF * WF;
  const size_t zsM = (size_t)HF * WF;

  // value-GEMM epilogue accumulates directly into out
  hipMemsetAsync(out, 0, (size_t)out_size * sizeof(float), stream);

  for (int it = 0; it < 2; ++it) {
    const float* f = f_all + it * zsF;
    const float* b = b_all + it * zsF;
    const float* mk = m_all + it * zsM;
    float* o = out + it * zsF;

    k_prep<<<2048, 256, 0, stream>>>(f, b, fcat, bcat, s2);
    k_mmpnorm<<<32, 256, 0, stream>>>(mk, s2, mmp, rnrm);
    // D[p,q] (fp32-accurate via split-bf16, K=384)
    k_mfma_gemm<<<dim3(32, 32), 256, 0, stream>>>(bcat, fcat, bufD, 384, 384, 384, NP);
    k_s0<<<4096, 256, 0, stream>>>(bufD, rnrm, S0);
    k_fuse1<<<4096, 256, 0, stream>>>(S0, Yp);
    k_smax_part<<<dim3(4, NCHUNK), 256, 0, stream>>>(Yp, mmp, pm, ps);
    k_epilogue<<<6144, 256, 0, stream>>>(Yp, pm, ps, mmp, AT, b, VtT);
    // value GEMM + fused transposed-conv scatter into out
    k_mfma_gemm_vout<<<dim3(32, 16), 256, 0, stream>>>(VtT, AT, o);
  }
}

// Round 12
// 662.168 us; speedup vs baseline: 1.1602x; 1.1602x over previous
//
#include <hip/hip_runtime.h>
#include <math.h>

// KSIZE=3, STRIDE=1, RATE=2, FUSE_K=3, SCALE=10
#define CDIM 128
#define HF   128
#define WF   128
#define NP   4096   // 64*64 downsampled positions
#define NCHUNK 64   // softmax u-chunks (64 rows each)

typedef __attribute__((ext_vector_type(8))) short short8;
typedef __attribute__((ext_vector_type(16))) float f16a;
typedef float __attribute__((ext_vector_type(4), aligned(16))) f4a16;
typedef float __attribute__((ext_vector_type(4), aligned(4)))  f4u;

__device__ inline ushort f2bf(float x) {
  union { float f; unsigned u; } v; v.f = x;
  unsigned r = v.u + 0x7fff + ((v.u >> 16) & 1);
  return (ushort)(r >> 16);
}
__device__ inline float bf2f(ushort h) {
  union { unsigned u; float f; } v; v.u = ((unsigned)h) << 16; return v.f;
}

__device__ inline void gl2lds16(const ushort* g, ushort* l) {
  __builtin_amdgcn_global_load_lds((const __attribute__((address_space(1))) void*)g,
                                   (__attribute__((address_space(3))) void*)l, 16, 0, 0);
}

// ---------------------------------------------------------------------------
// prep: downsample + split fp32 -> (hi,lo) bf16 K-major cat operands, AND
// s2[p] = sum_c b_ds[c,p]^2
__global__ __launch_bounds__(256) void k_prep(const float* __restrict__ f,
                                              const float* __restrict__ b,
                                              ushort* __restrict__ fcat,
                                              ushort* __restrict__ bcat,
                                              float* __restrict__ s2) {
  int idx = blockIdx.x * 256 + threadIdx.x;   // 524288
  int c = idx & 127, pos = idx >> 7;
  int x = pos & 63, y = pos >> 6;
  int src = c * 16384 + y * 256 + x * 2;
  float fv = f[src], bv = b[src];
  ushort fh = f2bf(fv); ushort fl = f2bf(fv - bf2f(fh));
  ushort bh = f2bf(bv); ushort bl = f2bf(bv - bf2f(bh));
  size_t base = (size_t)pos * 384;
  fcat[base + c] = fh; fcat[base + 128 + c] = fl; fcat[base + 256 + c] = fh;
  bcat[base + c] = bh; bcat[base + 128 + c] = bh; bcat[base + 256 + c] = bl;
  float sq = bv * bv;
#pragma unroll
  for (int off = 32; off; off >>= 1) sq += __shfl_down(sq, off);
  __shared__ float wsum[4];
  if ((threadIdx.x & 63) == 0) wsum[threadIdx.x >> 6] = sq;
  __syncthreads();
  if (threadIdx.x == 0) s2[blockIdx.x * 2]     = wsum[0] + wsum[1];
  if (threadIdx.x == 1) s2[blockIdx.x * 2 + 1] = wsum[2] + wsum[3];
}

// merged: blocks 0..15 -> mmp[a] (mask gate at p=pi(a)); 16..31 -> rnrm[p]
__global__ __launch_bounds__(256) void k_mmpnorm(const float* __restrict__ mask,
                                                 const float* __restrict__ s2,
                                                 float* __restrict__ mmp,
                                                 float* __restrict__ rnrm) {
  int bx = blockIdx.x, t = threadIdx.x;
  if (bx < 16) {
    int a = bx * 256 + t;
    int yb = a & 63, xb = a >> 6;               // p = pi(a)
    float s = 0.f;
    for (int dy = -1; dy <= 1; ++dy)
      for (int dx = -1; dx <= 1; ++dx) {
        int y = yb + dy, x = xb + dx;
        if ((unsigned)y < 64u && (unsigned)x < 64u)
          s += mask[y * 256 + x * 2];
      }
    mmp[a] = (s == 0.0f) ? 1.0f : 0.0f;
  } else {
    int p = (bx - 16) * 256 + t;
    int xb = p & 63, yb = p >> 6;
    float s = 0.f;
    for (int dy = -1; dy <= 1; ++dy)
      for (int dx = -1; dx <= 1; ++dx) {
        int y = yb + dy, x = xb + dx;
        if ((unsigned)y < 64u && (unsigned)x < 64u) s += s2[y * 64 + x];
      }
    rnrm[p] = rsqrtf(s + 1152.0f * 1.0e-4f);
  }
}

// ---------------------------------------------------------------------------
// MFMA bf16 GEMM: Out[m,n] = sum_k A[m*lda+k]*B[n*ldb+k]  (K-major operands)
// 128x128 tile, 4 waves (2x2 of 64x64), BK=64, 32x32x16 MFMA (2x2 subtiles).
// global_load_lds staging + global-address XOR swizzle (R7-verified, 0 conflicts).
// A/B frag: lane holds [m|n = lane&31][k = (lane>>5)*8 + j]  (one short8).
// C/D: col = lane&31, row = (r&3) + 8*(r>>2) + 4*(lane>>5), r in [0,16).
__global__ __launch_bounds__(256) void k_mfma_gemm(const ushort* __restrict__ A,
                                                   const ushort* __restrict__ B,
                                                   float* __restrict__ Out,
                                                   int Kdim, int lda, int ldb, int ldo) {
  __shared__ ushort As[128 * 64];
  __shared__ ushort Bs[128 * 64];
  int tid = threadIdx.x;
  int wave = tid >> 6, lane = tid & 63;
  int l32 = lane & 31, khalf = lane >> 5;
  int m0 = blockIdx.y * 128, n0 = blockIdx.x * 128;
  int wm = (wave >> 1) * 64, wn = (wave & 1) * 64;
  int srow = lane >> 3;
  int g = lane & 7;
  int gperm = (g ^ srow) * 8;

  f16a acc[2][2];
#pragma unroll
  for (int i = 0; i < 2; ++i)
#pragma unroll
    for (int j = 0; j < 2; ++j)
#pragma unroll
      for (int r = 0; r < 16; ++r) acc[i][j][r] = 0.f;

  for (int k0 = 0; k0 < Kdim; k0 += 64) {
#pragma unroll
    for (int i = 0; i < 4; ++i) {
      int rbase = wave * 32 + i * 8;
      gl2lds16(A + (size_t)(m0 + rbase + srow) * lda + k0 + gperm, &As[rbase * 64]);
      gl2lds16(B + (size_t)(n0 + rbase + srow) * ldb + k0 + gperm, &Bs[rbase * 64]);
    }
    __syncthreads();
#pragma unroll
    for (int s = 0; s < 4; ++s) {           // 4 K-steps of 16
      short8 af[2], bf[2];
#pragma unroll
      for (int t2 = 0; t2 < 2; ++t2) {
        int am = wm + t2 * 32 + l32;
        int ga = ((s * 2 + khalf) ^ (am & 7)) * 8;
        af[t2] = *reinterpret_cast<const short8*>(&As[am * 64 + ga]);
        int bn = wn + t2 * 32 + l32;
        int gb = ((s * 2 + khalf) ^ (bn & 7)) * 8;
        bf[t2] = *reinterpret_cast<const short8*>(&Bs[bn * 64 + gb]);
      }
#pragma unroll
      for (int i = 0; i < 2; ++i)
#pragma unroll
        for (int j = 0; j < 2; ++j)
          acc[i][j] = __builtin_amdgcn_mfma_f32_32x32x16_bf16(af[i], bf[j], acc[i][j], 0, 0, 0);
    }
    __syncthreads();
  }
#pragma unroll
  for (int i = 0; i < 2; ++i)
#pragma unroll
    for (int j = 0; j < 2; ++j)
#pragma unroll
      for (int r = 0; r < 16; ++r) {
        int row = (r & 3) + 8 * (r >> 2) + 4 * khalf;
        Out[(size_t)(m0 + wm + i * 32 + row) * ldo + (n0 + wn + j * 32 + l32)] = acc[i][j][r];
      }
}

// ---------------------------------------------------------------------------
// S0[p,q] = (sum of 9 diag-shifted D taps) * rnrm[p]
__global__ __launch_bounds__(256) void k_s0(const float* __restrict__ D,
                                            const float* __restrict__ rnrm,
                                            float* __restrict__ S0) {
  int p = blockIdx.x;
  int yb = p >> 6, xb = p & 63;
  float rp = rnrm[p];
  int t = threadIdx.x;
#pragma unroll
  for (int it = 0; it < 4; ++it) {
    int q = (it * 256 + t) << 2;
    int qy = q >> 6, qx = q & 63;
    f4a16 acc = (f4a16){0.f, 0.f, 0.f, 0.f};
#pragma unroll
    for (int dy = -1; dy <= 1; ++dy) {
      if ((unsigned)(yb + dy) >= 64u) continue;
      if ((unsigned)(qy + dy) >= 64u) continue;
#pragma unroll
      for (int dx = -1; dx <= 1; ++dx) {
        if ((unsigned)(xb + dx) >= 64u) continue;
        int delta = dy * 64 + dx;
        const float* base = D + (size_t)(p + delta) * 4096;
        f4u v;
        if (dx == -1 && qx == 0) {
          f4u r = *(const f4u*)(base + q + delta + 1);  // avoid negative addr
          v = (f4u){0.f, r.x, r.y, r.z};
        } else {
          v = *(const f4u*)(base + q + delta);
          if (dx == 1 && qx == 60) v.w = 0.f;
        }
        acc += v;
      }
    }
    acc *= rp;
    *(f4a16*)(S0 + ((size_t)p << 12) + q) = acc;
  }
}

// fuse1: F1[i,j] = sum_d S0[i+d, j+d], written permuted: Yp[pi(i)][b]=F1[i][pi(b)]
__global__ __launch_bounds__(256) void k_fuse1(const float* __restrict__ S0,
                                               float* __restrict__ Yp) {
  __shared__ float row[4160];
  int i = blockIdx.x;
  int t = threadIdx.x;
  const float* r0 = S0 + (size_t)(i - 1) * 4096;
  const float* r1 = S0 + (size_t)i * 4096;
  const float* r2 = S0 + (size_t)(i + 1) * 4096;
  bool up = (i > 0), dn = (i < 4095);
#pragma unroll
  for (int jj = 0; jj < 4; ++jj) {
    int j = (jj * 256 + t) << 2;
    f4u s = *(const f4u*)(r1 + j);
    if (up) {
      f4u a;
      if (j == 0) { f4u r = *(const f4u*)r0; a = (f4u){0.f, r.x, r.y, r.z}; }
      else a = *(const f4u*)(r0 + j - 1);
      s += a;
    }
    if (dn) {
      f4u d = *(const f4u*)(r2 + j + 1);
      if (j == 4092) d.w = 0.f;
      s += d;
    }
    int base = j + (j >> 6);
    row[base + 0] = s.x; row[base + 1] = s.y; row[base + 2] = s.z; row[base + 3] = s.w;
  }
  __syncthreads();
  int a = ((i & 63) << 6) | (i >> 6);
  float* orow = Yp + ((size_t)a << 12);
#pragma unroll
  for (int bb = 0; bb < 4; ++bb) {
    int b4 = (bb * 256 + t) << 2;
    f4a16 o;
#pragma unroll
    for (int k = 0; k < 4; ++k) {
      int jT = (((b4 + k) & 63) << 6) | ((b4 + k) >> 6);
      o[k] = row[jT + (jT >> 6)];
    }
    *(f4a16*)(orow + b4) = o;
  }
}

// softmax partials over u of logits x = 10 * mmp[u] * diag3(Yp)[u,v]
__global__ __launch_bounds__(256) void k_smax_part(const float* __restrict__ Yp,
                                                   const float* __restrict__ mmp,
                                                   float* __restrict__ pm,
                                                   float* __restrict__ ps) {
  int v = (blockIdx.x * 256 + threadIdx.x) << 2;
  int chunk = blockIdx.y;
  f4a16 m = (f4a16){-1e30f, -1e30f, -1e30f, -1e30f};
  f4a16 s = (f4a16){0.f, 0.f, 0.f, 0.f};
  int u0 = chunk * (4096 / NCHUNK);
  for (int u = u0; u < u0 + (4096 / NCHUNK); ++u) {
    const float* row = Yp + ((size_t)u << 12);
    f4u tv = *(const f4u*)(row + v);
    if (u > 0) {
      f4u a;
      if (v == 0) { f4u r = *(const f4u*)(row - 4096); a = (f4u){0.f, r.x, r.y, r.z}; }
      else a = *(const f4u*)(row - 4096 + v - 1);
      tv += a;
    }
    if (u < 4095) {
      f4u d = *(const f4u*)(row + 4096 + v + 1);
      if (v == 4092) d.w = 0.f;
      tv += d;
    }
    float g = 10.0f * mmp[u];
    f4u x = tv * g;
#pragma unroll
    for (int l = 0; l < 4; ++l) {
      float xl = x[l];
      if (xl > m[l]) { s[l] = s[l] * __expf(m[l] - xl) + 1.0f; m[l] = xl; }
      else           { s[l] += __expf(xl - m[l]); }
    }
  }
  *(f4a16*)(pm + chunk * NP + v) = m;
  *(f4a16*)(ps + chunk * NP + v) = s;
}

// ---------------------------------------------------------------------------
// epilogue (flattened 6144-block grid): attnT tiles w/ local softmax reduction,
// and VtT transpose blocks.
__global__ __launch_bounds__(256) void k_epilogue(const float* __restrict__ Yp,
                                                  const float* __restrict__ pm,
                                                  const float* __restrict__ ps,
                                                  const float* __restrict__ mmp,
                                                  ushort* __restrict__ AT,
                                                  const float* __restrict__ bimg,
                                                  ushort* __restrict__ VtT) {
  __shared__ float T[64][65];
  __shared__ float pmS[4][64];
  __shared__ float psS[4][64];
  __shared__ float mS[64];
  __shared__ float rsS[64];
  int gx = blockIdx.x;
  int t = threadIdx.x;
  if (gx < 4096) {
    int a0 = (gx & 63) * 64, b0 = (gx >> 6) * 64;
    int j = t & 63, grp = t >> 6;
    float m = -1e30f, s = 0.f;
    for (int ch = grp * 16; ch < grp * 16 + 16; ++ch) {
      float m2 = pm[ch * NP + b0 + j], s2 = ps[ch * NP + b0 + j];
      if (m2 > m) { s = s * __expf(m - m2) + s2; m = m2; }
      else        { s += s2 * __expf(m2 - m); }
    }
    pmS[grp][j] = m; psS[grp][j] = s;
    __syncthreads();
    if (grp == 0) {
      for (int g2 = 1; g2 < 4; ++g2) {
        float m2 = pmS[g2][j], s2 = psS[g2][j];
        if (m2 > m) { s = s * __expf(m - m2) + s2; m = m2; }
        else        { s += s2 * __expf(m2 - m); }
      }
      mS[j] = m; rsS[j] = 1.0f / s;
    }
    __syncthreads();
    int i = t >> 4, j4 = (t & 15) << 2;
    f4a16 mc = *(const f4a16*)&mS[j4];
    f4a16 rs = *(const f4a16*)&rsS[j4];
#pragma unroll
    for (int r = 0; r < 4; ++r) {
      int al = r * 16 + i;
      int a = a0 + al;
      const float* row = Yp + ((size_t)a << 12);
      int b = b0 + j4;
      f4u y = *(const f4u*)(row + b);
      if (a > 0) {
        f4u u_;
        if (b == 0) { f4u rr = *(const f4u*)(row - 4096); u_ = (f4u){0.f, rr.x, rr.y, rr.z}; }
        else u_ = *(const f4u*)(row - 4096 + b - 1);
        y += u_;
      }
      if (a < 4095) {
        f4u d = *(const f4u*)(row + 4096 + b + 1);
        if (b == 4092) d.w = 0.f;
        y += d;
      }
      float g = mmp[a];
      f4u x = y * (10.0f * g);
#pragma unroll
      for (int l = 0; l < 4; ++l)
        T[al][j4 + l] = g * __expf(x[l] - mc[l]) * rs[l];
    }
    __syncthreads();
    int by0 = b0 >> 6;
    int cgrp = (t & 7) * 8;
#pragma unroll
    for (int pass = 0; pass < 2; ++pass) {
      int bl = pass * 32 + (t >> 3);
      int q = bl * 64 + by0;                   // pi(b0 + bl)
      uint4 w;
      w.x = (unsigned)f2bf(T[cgrp + 0][bl]) | ((unsigned)f2bf(T[cgrp + 1][bl]) << 16);
      w.y = (unsigned)f2bf(T[cgrp + 2][bl]) | ((unsigned)f2bf(T[cgrp + 3][bl]) << 16);
      w.z = (unsigned)f2bf(T[cgrp + 4][bl]) | ((unsigned)f2bf(T[cgrp + 5][bl]) << 16);
      w.w = (unsigned)f2bf(T[cgrp + 6][bl]) | ((unsigned)f2bf(T[cgrp + 7][bl]) << 16);
      *(uint4*)(AT + ((size_t)q << 12) + a0 + cgrp) = w;
    }
  } else {
    int k2 = gx - 4096;
    int c = k2 >> 4, dy = (k2 >> 2) & 3, dx = k2 & 3;
    int px = t & 63;
#pragma unroll
    for (int r = 0; r < 16; ++r) {
      int py = r * 4 + (t >> 6);
      int sy = 2 * py + dy - 1, sx = 2 * px + dx - 1;
      float v = 0.f;
      if ((unsigned)sy < (unsigned)HF && (unsigned)sx < (unsigned)WF)
        v = bimg[c * 16384 + sy * 128 + sx];
      T[py][px] = v;
    }
    __syncthreads();
    ushort* orow = VtT + (size_t)k2 * 4096;
#pragma unroll
    for (int r = 0; r < 16; ++r) {
      int a = r * 256 + t;
      orow[a] = f2bf(T[a & 63][a >> 6]);
    }
  }
}

// scatter M[(c,dy,dx), q] -> out (transposed conv, lhs_dilation=2), /4
__global__ __launch_bounds__(256) void k_scatter(const float* __restrict__ M,
                                                 float* __restrict__ out) {
  int idx = blockIdx.x * 256 + threadIdx.x;
  int ox = idx & 127, oy = (idx >> 7) & 127, c = idx >> 14;
  int qy[2], dyv[2], qx[2], dxv[2];
  if (oy & 1) { qy[0] = (oy - 1) >> 1; dyv[0] = 2; qy[1] = (oy + 1) >> 1; dyv[1] = 0; }
  else        { qy[0] = (oy >> 1) - 1; dyv[0] = 3; qy[1] = oy >> 1;       dyv[1] = 1; }
  if (ox & 1) { qx[0] = (ox - 1) >> 1; dxv[0] = 2; qx[1] = (ox + 1) >> 1; dxv[1] = 0; }
  else        { qx[0] = (ox >> 1) - 1; dxv[0] = 3; qx[1] = ox >> 1;       dxv[1] = 1; }
  float s = 0.f;
#pragma unroll
  for (int i = 0; i < 2; ++i) {
    if ((unsigned)qy[i] >= 64u) continue;
#pragma unroll
    for (int j = 0; j < 2; ++j) {
      if ((unsigned)qx[j] >= 64u) continue;
      int k = c * 16 + dyv[i] * 4 + dxv[j];
      s += M[(size_t)k * NP + qy[i] * 64 + qx[j]];
    }
  }
  out[idx] = 0.25f * s;
}

// ---------------------------------------------------------------------------
extern "C" void kernel_launch(void* const* d_in, const int* in_sizes, int n_in,
                              void* d_out, int out_size, void* d_ws, size_t ws_size,
                              hipStream_t stream) {
  const float* f_all = (const float*)d_in[0];
  const float* b_all = (const float*)d_in[1];
  const float* m_all = (const float*)d_in[2];
  float* out = (float*)d_out;

  float* ws = (float*)d_ws;
  float* bufD = ws;                          // 64MB: D -> Yp -> M
  float* bufS = ws + 16777216;               // 64MB: {fcat,bcat} -> S0 -> {AT, VtT}
  ushort* fcat = (ushort*)bufS;
  ushort* bcat = (ushort*)(bufS + 786432);
  float* S0  = bufS;
  float* Yp  = bufD;
  ushort* AT  = (ushort*)bufS;               // 32MB
  ushort* VtT = (ushort*)(bufS + 8388608);   // 16MB
  float* Mbuf = bufD;                        // 32MB (clobbers Yp)
  float* smalls = ws + 2 * 16777216;
  float* s2    = smalls;
  float* rnrm  = s2 + 4096;
  float* mmp   = rnrm + 4096;
  float* pm    = mmp + 4096;
  float* ps    = pm + NCHUNK * NP;

  const size_t zsF = (size_t)CDIM * HF * WF;
  const size_t zsM = (size_t)HF * WF;

  for (int it = 0; it < 2; ++it) {
    const float* f = f_all + it * zsF;
    const float* b = b_all + it * zsF;
    const float* mk = m_all + it * zsM;
    float* o = out + it * zsF;

    k_prep<<<2048, 256, 0, stream>>>(f, b, fcat, bcat, s2);
    k_mmpnorm<<<32, 256, 0, stream>>>(mk, s2, mmp, rnrm);
    // D[p,q] (fp32-accurate via split-bf16, K=384)
    k_mfma_gemm<<<dim3(32, 32), 256, 0, stream>>>(bcat, fcat, bufD, 384, 384, 384, NP);
    k_s0<<<4096, 256, 0, stream>>>(bufD, rnrm, S0);
    k_fuse1<<<4096, 256, 0, stream>>>(S0, Yp);
    k_smax_part<<<dim3(4, NCHUNK), 256, 0, stream>>>(Yp, mmp, pm, ps);
    k_epilogue<<<6144, 256, 0, stream>>>(Yp, pm, ps, mmp, AT, b, VtT);
    // M[k2,q] = sum_a VtT[k2,a] * AT[q,a]   (K=4096)
    k_mfma_gemm<<<dim3(32, 16), 256, 0, stream>>>(VtT, AT, Mbuf, NP, NP, NP, NP);
    k_scatter<<<8192, 256, 0, stream>>>(Mbuf, o);
  }
}